// Round 15
// baseline (72.949 us; speedup 1.0000x reference)
//
#include <hip/hip_runtime.h>

// ShiftGraph: B=8, C=16, H=W=256, d=5 (r=2), 24 shifts.
// Output (flat float32): edges (B, E, 2) then ws (B, E), E = 1557540.
// R15: R11 (pair symmetry, combined edges+ws, NT stores, batch->XCD) with
// 2 px/thread: per (channel,row) three aligned float2 loads cover cols
// w0-2..w0+3 = all dj for both pixels. 64 loads/px vs R11's 208, at 4096
// waves (128-thr blocks x 2048). Clamped slots feed only guarded stores.

#define HH 256
#define WW 256
#define CC 16
#define BB 8
#define HW (HH * WW)
#define EE 1557540

__global__ __launch_bounds__(128) void shiftgraph_kernel(
    const float* __restrict__ x, float* __restrict__ out) {
    const int bid = blockIdx.x;
    const int b = bid & 7;            // batch -> XCD
    const int h = bid >> 3;           // row
    const int tid = threadIdx.x;      // 0..127
    const int w0 = tid << 1;          // pixels w0, w0+1

    const float* __restrict__ xb = x + (size_t)b * (CC * HW);
    const int r0 = h * WW;
    const int r1 = (h + 1 < HH ? h + 1 : HH - 1) * WW;   // clamped; stores guarded
    const int r2 = (h + 2 < HH ? h + 2 : HH - 1) * WW;

    const int cA = (tid == 0)   ? 0   : w0 - 2;   // clamped; feeds guarded lanes only
    const int cB = w0;
    const int cC = (tid == 127) ? 252 : w0 + 2;

    float acc[12][2];
#pragma unroll
    for (int s = 0; s < 12; ++s) { acc[s][0] = 0.0f; acc[s][1] = 0.0f; }

#pragma unroll 4
    for (int c = 0; c < CC; ++c) {
        const float* __restrict__ xc = xb + c * HW;
        const float2 qb0 = *reinterpret_cast<const float2*>(xc + r0 + cB);
        const float2 qc0 = *reinterpret_cast<const float2*>(xc + r0 + cC);
        const float2 qa1 = *reinterpret_cast<const float2*>(xc + r1 + cA);
        const float2 qb1 = *reinterpret_cast<const float2*>(xc + r1 + cB);
        const float2 qc1 = *reinterpret_cast<const float2*>(xc + r1 + cC);
        const float2 qa2 = *reinterpret_cast<const float2*>(xc + r2 + cA);
        const float2 qb2 = *reinterpret_cast<const float2*>(xc + r2 + cB);
        const float2 qc2 = *reinterpret_cast<const float2*>(xc + r2 + cC);

        const float cw[2]  = {qb0.x, qb0.y};
        // slot idx = col - w0 + 2 ; value at col w0+p+dj -> idx p+dj+2
        const float n0[4] = {qb0.x, qb0.y, qc0.x, qc0.y};             // cols w0..w0+3 (idx-2)
        const float n1[6] = {qa1.x, qa1.y, qb1.x, qb1.y, qc1.x, qc1.y};
        const float n2[6] = {qa2.x, qa2.y, qb2.x, qb2.y, qc2.x, qc2.y};

#pragma unroll
        for (int p = 0; p < 2; ++p) {
            float d;
            d = n0[p + 1] - cw[p]; acc[0][p] = fmaf(d, d, acc[0][p]);   // (0,1)
            d = n0[p + 2] - cw[p]; acc[1][p] = fmaf(d, d, acc[1][p]);   // (0,2)
#pragma unroll
            for (int dj = -2; dj <= 2; ++dj) {
                d = n1[p + dj + 2] - cw[p];
                acc[2 + dj + 2][p] = fmaf(d, d, acc[2 + dj + 2][p]);    // (1,dj)
                d = n2[p + dj + 2] - cw[p];
                acc[7 + dj + 2][p] = fmaf(d, d, acc[7 + dj + 2][p]);    // (2,dj)
            }
        }
    }

    float* __restrict__ edges = out;                        // (B, E, 2)
    float* __restrict__ wsp   = out + (size_t)BB * EE * 2;  // (B, E)
    const size_t bE = (size_t)b * EE;
    const int posc = r0 + w0;   // pixel p adds +p

    int s = 0;
#pragma unroll
    for (int di = 0; di <= 2; ++di) {
#pragma unroll
        for (int dj = (di == 0 ? 1 : -2); dj <= 2; ++dj, ++s) {
            const int i = di + 2, j = dj + 2;
            if (h + di >= HH) continue;          // uniform across block

            const float scale = sqrtf((float)(di * di + dj * dj));
            // compile-time prefix offsets for (i,j) and mirror (4-i,4-j)
            int offF = 0, offM = 0;
#pragma unroll
            for (int m = 0; m < 25; ++m) {
                const int mi = m / 5, mj = m % 5;
                if (mi == 2 && mj == 2) continue;
                const int cm = (HH - (mi < 2 ? 2 - mi : mi - 2)) *
                               (WW - (mj < 2 ? 2 - mj : mj - 2));
                if (m < i * 5 + j) offF += cm;
                if (m < (4 - i) * 5 + (4 - j)) offM += cm;
            }
            const int cww = WW - (dj < 0 ? -dj : dj);
            const int e1b = offF + h * cww + (w0 - (dj < 0 ? -dj : 0));
            const int e2b = offM + h * cww + (w0 + (dj < 0 ? dj : 0));
            const int posv = di * WW + dj;

#pragma unroll
            for (int p = 0; p < 2; ++p) {
                const int w2 = w0 + p + dj;
                if (w2 < 0 || w2 >= WW) continue;   // diverges on 1 lane/wave max
                const float wsv = -acc[s][p] * scale;
                union { float f[2]; unsigned long long u; } evF, evM;
                evF.f[0] = (float)(posc + p);        evF.f[1] = (float)(posc + p + posv);
                evM.f[0] = (float)(posc + p + posv); evM.f[1] = (float)(posc + p);
                __builtin_nontemporal_store(
                    evF.u, reinterpret_cast<unsigned long long*>(edges + (bE + e1b + p) * 2));
                __builtin_nontemporal_store(
                    evM.u, reinterpret_cast<unsigned long long*>(edges + (bE + e2b + p) * 2));
                __builtin_nontemporal_store(wsv, wsp + bE + e1b + p);
                __builtin_nontemporal_store(wsv, wsp + bE + e2b + p);
            }
        }
    }
}

extern "C" void kernel_launch(void* const* d_in, const int* in_sizes, int n_in,
                              void* d_out, int out_size, void* d_ws, size_t ws_size,
                              hipStream_t stream) {
    const float* x = (const float*)d_in[0];
    float* out = (float*)d_out;
    dim3 block(128);           // 2 px/thread
    dim3 grid(HH * BB);        // one block per (row, batch)
    shiftgraph_kernel<<<grid, block, 0, stream>>>(x, out);
}

// Round 16
// 35.394 us; speedup vs baseline: 2.0611x; 2.0611x over previous
//
#include <hip/hip_runtime.h>

// ShiftGraph: B=8, C=16, H=W=256, d=5 (r=2), 24 shifts.
// Output (flat float32): edges (B, E, 2) then ws (B, E), E = 1557540.
// R16: R11 shape (2048 blocks x 256 thr, 1 px/thread, pair symmetry, NT
// own+mirror stores) + LDS staging in 4-channel chunks (12 KB -> still 8
// blocks/CU): rows h..h+2 staged by 3 float4 loads/thread/pass; all neighbor
// reads become stride-1 immediate-offset ds_read_b32. Global loads 208 -> 12.

#define HH 256
#define WW 256
#define CC 16
#define BB 8
#define HW (HH * WW)
#define EE 1557540

__global__ __launch_bounds__(256) void shiftgraph_kernel(
    const float* __restrict__ x, float* __restrict__ out) {
    __shared__ float lds[3080];     // [4ch][3rows][256cols] + 8 pad
    const int bid = blockIdx.x;
    const int b = bid & 7;          // batch -> XCD
    const int h = bid >> 3;         // row
    const int w = threadIdx.x;      // col

    const float* __restrict__ xb = x + (size_t)b * (CC * HW);

    // staging map, computed once: 3072 floats = [cl][row][col], cl=flat/768
    const float* src[3];
    int dst[3];
#pragma unroll
    for (int inst = 0; inst < 3; ++inst) {
        const int flatf = inst * 1024 + w * 4;
        const int cl  = flatf / 768;
        const int rem = flatf - cl * 768;
        const int row = rem >> 8;
        const int col = rem & 255;
        int hr = h + row; hr = hr > HH - 1 ? HH - 1 : hr;  // clamp: stores guarded
        src[inst] = xb + cl * HW + hr * WW + col;
        dst[inst] = flatf;
    }

    float acc[12];
#pragma unroll
    for (int s2 = 0; s2 < 12; ++s2) acc[s2] = 0.0f;

    for (int cc = 0; cc < 4; ++cc) {        // 4-channel chunks
        __syncthreads();
#pragma unroll
        for (int inst = 0; inst < 3; ++inst) {
            const float4 v = *reinterpret_cast<const float4*>(src[inst]);
            *reinterpret_cast<float4*>(&lds[dst[inst]]) = v;
            src[inst] += 4 * HW;
        }
        __syncthreads();
#pragma unroll
        for (int c = 0; c < 4; ++c) {
            const int base = c * 768 + w;   // addr = w*4 + compile-time imm
            const float ctr = lds[base];
            float d;
            d = lds[base + 1] - ctr; acc[0] = fmaf(d, d, acc[0]);   // (0,1)
            d = lds[base + 2] - ctr; acc[1] = fmaf(d, d, acc[1]);   // (0,2)
#pragma unroll
            for (int dj = -2; dj <= 2; ++dj) {
                d = lds[base + 256 + dj] - ctr;                     // (1,dj)
                acc[4 + dj] = fmaf(d, d, acc[4 + dj]);
                d = lds[base + 512 + dj] - ctr;                     // (2,dj)
                acc[9 + dj] = fmaf(d, d, acc[9 + dj]);
            }
        }
    }

    // ---- store burst: own + mirror (R11 addressing) ----
    float* __restrict__ edges = out;                        // (B, E, 2)
    float* __restrict__ wsp   = out + (size_t)BB * EE * 2;  // (B, E)
    const size_t bE = (size_t)b * EE;
    const int posc = h * WW + w;

    int s = 0;
#pragma unroll
    for (int di = 0; di <= 2; ++di) {
#pragma unroll
        for (int dj = (di == 0 ? 1 : -2); dj <= 2; ++dj, ++s) {
            const int i = di + 2, j = dj + 2;
            if (h + di >= HH) continue;              // uniform across block
            const int w2 = w + dj;
            if (w2 < 0 || w2 >= WW) continue;        // <=2 edge lanes diverge

            const float scale = sqrtf((float)(di * di + dj * dj));
            const float wsv = -acc[s] * scale;

            int offF = 0, offM = 0;                  // compile-time prefixes
#pragma unroll
            for (int m = 0; m < 25; ++m) {
                const int mi = m / 5, mj = m % 5;
                if (mi == 2 && mj == 2) continue;
                const int cm = (HH - (mi < 2 ? 2 - mi : mi - 2)) *
                               (WW - (mj < 2 ? 2 - mj : mj - 2));
                if (m < i * 5 + j) offF += cm;
                if (m < (4 - i) * 5 + (4 - j)) offM += cm;
            }
            const int cww = WW - (dj < 0 ? -dj : dj);
            const int e1 = offF + h * cww + (w - (dj < 0 ? -dj : 0));
            const int e2 = offM + h * cww + (w + (dj < 0 ? dj : 0));
            const int posv = di * WW + dj;

            union { float f[2]; unsigned long long u; } evF, evM;
            evF.f[0] = (float)posc;          evF.f[1] = (float)(posc + posv);
            evM.f[0] = (float)(posc + posv); evM.f[1] = (float)posc;

            __builtin_nontemporal_store(
                evF.u, reinterpret_cast<unsigned long long*>(edges + (bE + e1) * 2));
            __builtin_nontemporal_store(
                evM.u, reinterpret_cast<unsigned long long*>(edges + (bE + e2) * 2));
            __builtin_nontemporal_store(wsv, wsp + bE + e1);
            __builtin_nontemporal_store(wsv, wsp + bE + e2);
        }
    }
}

extern "C" void kernel_launch(void* const* d_in, const int* in_sizes, int n_in,
                              void* d_out, int out_size, void* d_ws, size_t ws_size,
                              hipStream_t stream) {
    const float* x = (const float*)d_in[0];
    float* out = (float*)d_out;
    dim3 block(WW);            // one thread per column
    dim3 grid(HH * BB);        // one block per (row, batch)
    shiftgraph_kernel<<<grid, block, 0, stream>>>(x, out);
}